// Round 1
// baseline (2764.445 us; speedup 1.0000x reference)
//
#include <hip/hip_runtime.h>
#include <math.h>

// Problem constants (B=16, S=2048, L=E=512, N=2048)
#define BS_TOK 32768
#define DIM 512
#define NCODE 2048

// ---------------- row L2 normalize (rows of length 512) ----------------
// one block (256 threads) per row; in-place safe.
__global__ __launch_bounds__(256) void k_rownorm(const float* __restrict__ in,
                                                 float* __restrict__ out) {
  const int r = blockIdx.x;
  const int t = threadIdx.x;
  const float* row = in + (size_t)r * DIM;
  float v0 = row[t];
  float v1 = row[t + 256];
  float s = v0 * v0 + v1 * v1;
#pragma unroll
  for (int off = 32; off > 0; off >>= 1) s += __shfl_down(s, off, 64);
  __shared__ float ls[4];
  if ((t & 63) == 0) ls[t >> 6] = s;
  __syncthreads();
  float tot = ls[0] + ls[1] + ls[2] + ls[3];
  float sc = 1.0f / fmaxf(sqrtf(tot), 1e-12f);
  float* orow = out + (size_t)r * DIM;
  orow[t] = v0 * sc;
  orow[t + 256] = v1 * sc;
}

// ---------------- fp32 GEMM, C[m,n] = sum_k A[am,k]*B[n,k] + bias[n] ----
// NT layout: both A and B rows are K-contiguous. Tile 64x64, BK=32.
// 256 threads, 4x4 microtile with stride-16 rows/cols.
// GATHER: am = gather[m]; also applies straight-through: out = z + (val - z).
template <bool GATHER>
__global__ __launch_bounds__(256) void k_gemm_nt(
    const float* __restrict__ A, const float* __restrict__ B,
    const float* __restrict__ bias, float* __restrict__ C,
    const int* __restrict__ gather, const float* __restrict__ zin,
    int K, int Nc) {
  constexpr int BK = 32;
  constexpr int LDA = BK + 4;  // 36 floats: 16B-aligned rows, odd float4 stride
  __shared__ float As[64 * LDA];
  __shared__ float Bs[64 * LDA];
  __shared__ int gidx[64];
  const int bm = blockIdx.y * 64;
  const int bn = blockIdx.x * 64;
  const int t = threadIdx.x;
  const int tn = t & 15;
  const int tm = t >> 4;
  if (GATHER) {
    if (t < 64) gidx[t] = gather[bm + t];
  }
  float acc[4][4] = {};
  for (int k0 = 0; k0 < K; k0 += BK) {
    __syncthreads();
    // stage: 64 rows x 32 k = 512 float4 per matrix; 2 per thread
#pragma unroll
    for (int i = 0; i < 2; ++i) {
      int lin = t + i * 256;
      int row = lin >> 3;
      int c4 = (lin & 7) << 2;
      int arow = GATHER ? gidx[row] : (bm + row);
      float4 va = *(const float4*)(A + (size_t)arow * K + k0 + c4);
      float4 vb = *(const float4*)(B + (size_t)(bn + row) * K + k0 + c4);
      *(float4*)(&As[row * LDA + c4]) = va;
      *(float4*)(&Bs[row * LDA + c4]) = vb;
    }
    __syncthreads();
#pragma unroll
    for (int k4 = 0; k4 < BK; k4 += 4) {
      float4 a[4], b[4];
#pragma unroll
      for (int i = 0; i < 4; ++i)
        a[i] = *(const float4*)(&As[(tm + 16 * i) * LDA + k4]);
#pragma unroll
      for (int j = 0; j < 4; ++j)
        b[j] = *(const float4*)(&Bs[(tn + 16 * j) * LDA + k4]);
#pragma unroll
      for (int i = 0; i < 4; ++i)
#pragma unroll
        for (int j = 0; j < 4; ++j) {
          acc[i][j] = fmaf(a[i].x, b[j].x, acc[i][j]);
          acc[i][j] = fmaf(a[i].y, b[j].y, acc[i][j]);
          acc[i][j] = fmaf(a[i].z, b[j].z, acc[i][j]);
          acc[i][j] = fmaf(a[i].w, b[j].w, acc[i][j]);
        }
    }
  }
#pragma unroll
  for (int j = 0; j < 4; ++j) {
    int n = bn + tn + 16 * j;
    float bv = bias[n];
#pragma unroll
    for (int i = 0; i < 4; ++i) {
      int m = bm + tm + 16 * i;
      float val = acc[i][j] + bv;
      if (GATHER) {
        // mimic zq = z + (zq - z) of the reference exactly (fp32 strict)
        float zv = zin[(size_t)m * Nc + n];
        val = zv + (val - zv);
      }
      C[(size_t)m * Nc + n] = val;
    }
  }
}

// ---------------- fused similarity + argmax ----------------
// Per block: 16 tokens (full K=512 staged in LDS, 32KB), stream all 2048
// codes in 128-wide tiles with K-chunks of 32 staged in LDS.
// Thread tile: 2 rows (tm, tm+8) x 4 cols (tn, tn+32, tn+64, tn+96).
// Running per-row argmax in registers, tie -> smaller index (first occurrence
// of the min of d = -sim, matching numpy argmin).
__global__ __launch_bounds__(256) void k_argmax(
    const float* __restrict__ zf_n, const float* __restrict__ emb_n,
    int* __restrict__ idx_out, float* __restrict__ idxf_out) {
  constexpr int KC = 32;
  constexpr int LDE = KC + 4;  // 36 floats
  __shared__ float Zs[16 * DIM];      // 32 KB, k-contiguous
  __shared__ float Es[128 * LDE];     // 18 KB
  const int t = threadIdx.x;
  const int tn = t & 31;
  const int tm = t >> 5;  // 0..7
  const int m0 = blockIdx.x * 16;
  // stage Zs: 16x512 = 2048 float4 / 256 thr = 8 each (contiguous copy)
#pragma unroll
  for (int i = 0; i < 8; ++i) {
    int lin = t + i * 256;
    int row = lin >> 7;
    int c4 = (lin & 127) << 2;
    *(float4*)(&Zs[row * DIM + c4]) =
        *(const float4*)(zf_n + (size_t)(m0 + row) * DIM + c4);
  }
  float bestv[2] = {-2.0f, -2.0f};
  int bestn[2] = {0, 0};
  for (int nt = 0; nt < NCODE; nt += 128) {
    float acc[2][4] = {};
    for (int k0 = 0; k0 < DIM; k0 += KC) {
      __syncthreads();
      // stage Es: 128 rows x 32 k = 1024 float4 / 256 thr = 4 each
#pragma unroll
      for (int i = 0; i < 4; ++i) {
        int lin = t + i * 256;
        int row = lin >> 3;
        int c4 = (lin & 7) << 2;
        *(float4*)(&Es[row * LDE + c4]) =
            *(const float4*)(emb_n + (size_t)(nt + row) * DIM + k0 + c4);
      }
      __syncthreads();
#pragma unroll
      for (int k4 = 0; k4 < KC; k4 += 4) {
        float4 a0 = *(const float4*)(&Zs[tm * DIM + k0 + k4]);
        float4 a1 = *(const float4*)(&Zs[(tm + 8) * DIM + k0 + k4]);
        float4 b[4];
#pragma unroll
        for (int j = 0; j < 4; ++j)
          b[j] = *(const float4*)(&Es[(tn + 32 * j) * LDE + k4]);
#pragma unroll
        for (int j = 0; j < 4; ++j) {
          acc[0][j] = fmaf(a0.x, b[j].x, acc[0][j]);
          acc[0][j] = fmaf(a0.y, b[j].y, acc[0][j]);
          acc[0][j] = fmaf(a0.z, b[j].z, acc[0][j]);
          acc[0][j] = fmaf(a0.w, b[j].w, acc[0][j]);
          acc[1][j] = fmaf(a1.x, b[j].x, acc[1][j]);
          acc[1][j] = fmaf(a1.y, b[j].y, acc[1][j]);
          acc[1][j] = fmaf(a1.z, b[j].z, acc[1][j]);
          acc[1][j] = fmaf(a1.w, b[j].w, acc[1][j]);
        }
      }
    }
    // streaming argmax update (n ascending => strict '>' keeps first occ.)
#pragma unroll
    for (int i = 0; i < 2; ++i)
#pragma unroll
      for (int j = 0; j < 4; ++j) {
        int n = nt + tn + 32 * j;
        if (acc[i][j] > bestv[i]) {
          bestv[i] = acc[i][j];
          bestn[i] = n;
        }
      }
  }
  // reduce across the 32 lanes (tn) sharing each row; tie -> smaller index
#pragma unroll
  for (int i = 0; i < 2; ++i) {
#pragma unroll
    for (int off = 16; off > 0; off >>= 1) {
      float ov = __shfl_down(bestv[i], off, 32);
      int on = __shfl_down(bestn[i], off, 32);
      if (ov > bestv[i] || (ov == bestv[i] && on < bestn[i])) {
        bestv[i] = ov;
        bestn[i] = on;
      }
    }
  }
  if (tn == 0) {
#pragma unroll
    for (int i = 0; i < 2; ++i) {
      int m = m0 + tm + 8 * i;
      idx_out[m] = bestn[i];
      idxf_out[m] = (float)bestn[i];
    }
  }
}

extern "C" void kernel_launch(void* const* d_in, const int* in_sizes, int n_in,
                              void* d_out, int out_size, void* d_ws,
                              size_t ws_size, hipStream_t stream) {
  const float* z = (const float*)d_in[0];
  // d_in[1] = mask, unused by the forward body
  const float* W_in = (const float*)d_in[2];
  const float* b_in = (const float*)d_in[3];
  const float* W_out = (const float*)d_in[4];
  const float* b_out = (const float*)d_in[5];
  const float* emb = (const float*)d_in[6];

  float* out = (float*)d_out;
  float* zq = out;                                  // 32768*512 floats
  float* idxf = out + (size_t)BS_TOK * DIM;         // 32768 floats

  float* emb_n = (float*)d_ws;                      // 2048*512 floats = 4 MiB
  int* idx = (int*)((char*)d_ws + (size_t)NCODE * DIM * sizeof(float));

  // zf_n lives in the zq region of d_out (dead by the time zq is written)
  float* zf = zq;

  // 1) normalize codebook rows
  k_rownorm<<<NCODE, 256, 0, stream>>>(emb, emb_n);
  // 2) zf = z @ W_in^T + b_in
  k_gemm_nt<false><<<dim3(DIM / 64, BS_TOK / 64), 256, 0, stream>>>(
      z, W_in, b_in, zf, nullptr, nullptr, DIM, DIM);
  // 3) normalize zf rows in-place
  k_rownorm<<<BS_TOK, 256, 0, stream>>>(zf, zf);
  // 4) fused similarity + argmax -> indices (int to ws, float to d_out)
  k_argmax<<<BS_TOK / 16, 256, 0, stream>>>(zf, emb_n, idx, idxf);
  // 5) zq = emb_n[idx] @ W_out^T + b_out, with straight-through arithmetic
  k_gemm_nt<true><<<dim3(DIM / 64, BS_TOK / 64), 256, 0, stream>>>(
      emb_n, W_out, b_out, zq, idx, z, DIM, DIM);
}

// Round 2
// 897.808 us; speedup vs baseline: 3.0791x; 3.0791x over previous
//
#include <hip/hip_runtime.h>
#include <math.h>

// Problem constants (B=16, S=2048, L=E=512, N=2048)
#define BS_TOK 32768
#define DIM 512
#define NCODE 2048

typedef _Float16 f16x8 __attribute__((ext_vector_type(8)));
typedef _Float16 f16x4 __attribute__((ext_vector_type(4)));
typedef float f32x16 __attribute__((ext_vector_type(16)));

// ---------------- row L2 normalize + fp16 hi/lo split ----------------
// one block (256 threads) per row of 512. Writes hi[t], lo[t] fp16 arrays
// (row stride rstride halves). Safe for in-place overwrite of `in` because
// all reads complete before the __syncthreads() that precedes writes.
__global__ __launch_bounds__(256) void k_rownorm_split(
    const float* __restrict__ in, _Float16* __restrict__ hi,
    _Float16* __restrict__ lo, int rstride) {
  const int r = blockIdx.x;
  const int t = threadIdx.x;
  const float* row = in + (size_t)r * DIM;
  float v0 = row[t];
  float v1 = row[t + 256];
  float s = v0 * v0 + v1 * v1;
#pragma unroll
  for (int off = 32; off > 0; off >>= 1) s += __shfl_down(s, off, 64);
  __shared__ float ls[4];
  if ((t & 63) == 0) ls[t >> 6] = s;
  __syncthreads();  // also fences: all global reads of this row are done
  float tot = ls[0] + ls[1] + ls[2] + ls[3];
  float sc = 1.0f / fmaxf(sqrtf(tot), 1e-12f);
  float x0 = v0 * sc, x1 = v1 * sc;
  _Float16 h0 = (_Float16)x0;
  _Float16 h1 = (_Float16)x1;
  _Float16 e0 = (_Float16)((x0 - (float)h0) * 2048.0f);
  _Float16 e1 = (_Float16)((x1 - (float)h1) * 2048.0f);
  _Float16* hrow = hi + (size_t)r * rstride;
  _Float16* lrow = lo + (size_t)r * rstride;
  hrow[t] = h0;
  hrow[t + 256] = h1;
  lrow[t] = e0;
  lrow[t + 256] = e1;
}

// ---------------- fp32 GEMM (input projection) -----------------------
// C[m,n] = sum_k A[m,k]*B[n,k] + bias[n]. Tile 64x64, BK=32, 4x4 microtile.
__global__ __launch_bounds__(256) void k_gemm_in(
    const float* __restrict__ A, const float* __restrict__ B,
    const float* __restrict__ bias, float* __restrict__ C) {
  constexpr int K = DIM, Nc = DIM;
  constexpr int BK = 32;
  constexpr int LDA = BK + 4;
  __shared__ float As[64 * LDA];
  __shared__ float Bs[64 * LDA];
  const int bm = blockIdx.y * 64;
  const int bn = blockIdx.x * 64;
  const int t = threadIdx.x;
  const int tn = t & 15;
  const int tm = t >> 4;
  float acc[4][4] = {};
  for (int k0 = 0; k0 < K; k0 += BK) {
    __syncthreads();
#pragma unroll
    for (int i = 0; i < 2; ++i) {
      int lin = t + i * 256;
      int row = lin >> 3;
      int c4 = (lin & 7) << 2;
      float4 va = *(const float4*)(A + (size_t)(bm + row) * K + k0 + c4);
      float4 vb = *(const float4*)(B + (size_t)(bn + row) * K + k0 + c4);
      *(float4*)(&As[row * LDA + c4]) = va;
      *(float4*)(&Bs[row * LDA + c4]) = vb;
    }
    __syncthreads();
#pragma unroll
    for (int k4 = 0; k4 < BK; k4 += 4) {
      float4 a[4], b[4];
#pragma unroll
      for (int i = 0; i < 4; ++i)
        a[i] = *(const float4*)(&As[(tm + 16 * i) * LDA + k4]);
#pragma unroll
      for (int j = 0; j < 4; ++j)
        b[j] = *(const float4*)(&Bs[(tn + 16 * j) * LDA + k4]);
#pragma unroll
      for (int i = 0; i < 4; ++i)
#pragma unroll
        for (int j = 0; j < 4; ++j) {
          acc[i][j] = fmaf(a[i].x, b[j].x, acc[i][j]);
          acc[i][j] = fmaf(a[i].y, b[j].y, acc[i][j]);
          acc[i][j] = fmaf(a[i].z, b[j].z, acc[i][j]);
          acc[i][j] = fmaf(a[i].w, b[j].w, acc[i][j]);
        }
    }
  }
#pragma unroll
  for (int j = 0; j < 4; ++j) {
    int n = bn + tn + 16 * j;
    float bv = bias[n];
#pragma unroll
    for (int i = 0; i < 4; ++i) {
      int m = bm + tm + 16 * i;
      C[(size_t)m * Nc + n] = acc[i][j] + bv;
    }
  }
}

// ---------------- fp32 GEMM with gathered fp16-pair A (output proj) ---
// A row arow = gather[m], reconstructed as hi + lo/2048 (err ~2^-23).
__global__ __launch_bounds__(256) void k_gemm_gather(
    const _Float16* __restrict__ Ahi, const _Float16* __restrict__ Alo,
    const float* __restrict__ B, const float* __restrict__ bias,
    float* __restrict__ C, const int* __restrict__ gather,
    const float* __restrict__ zin) {
  constexpr int K = DIM, Nc = DIM;
  constexpr int BK = 32;
  constexpr int LDA = BK + 4;
  constexpr float INV = 1.0f / 2048.0f;
  __shared__ float As[64 * LDA];
  __shared__ float Bs[64 * LDA];
  __shared__ int gidx[64];
  const int bm = blockIdx.y * 64;
  const int bn = blockIdx.x * 64;
  const int t = threadIdx.x;
  const int tn = t & 15;
  const int tm = t >> 4;
  if (t < 64) gidx[t] = gather[bm + t];
  float acc[4][4] = {};
  for (int k0 = 0; k0 < K; k0 += BK) {
    __syncthreads();
#pragma unroll
    for (int i = 0; i < 2; ++i) {
      int lin = t + i * 256;
      int row = lin >> 3;
      int c4 = (lin & 7) << 2;
      int arow = gidx[row];
      f16x4 h4 = *(const f16x4*)(Ahi + (size_t)arow * K + k0 + c4);
      f16x4 l4 = *(const f16x4*)(Alo + (size_t)arow * K + k0 + c4);
      float4 va;
      va.x = (float)h4.x + (float)l4.x * INV;
      va.y = (float)h4.y + (float)l4.y * INV;
      va.z = (float)h4.z + (float)l4.z * INV;
      va.w = (float)h4.w + (float)l4.w * INV;
      float4 vb = *(const float4*)(B + (size_t)(bn + row) * K + k0 + c4);
      *(float4*)(&As[row * LDA + c4]) = va;
      *(float4*)(&Bs[row * LDA + c4]) = vb;
    }
    __syncthreads();
#pragma unroll
    for (int k4 = 0; k4 < BK; k4 += 4) {
      float4 a[4], b[4];
#pragma unroll
      for (int i = 0; i < 4; ++i)
        a[i] = *(const float4*)(&As[(tm + 16 * i) * LDA + k4]);
#pragma unroll
      for (int j = 0; j < 4; ++j)
        b[j] = *(const float4*)(&Bs[(tn + 16 * j) * LDA + k4]);
#pragma unroll
      for (int i = 0; i < 4; ++i)
#pragma unroll
        for (int j = 0; j < 4; ++j) {
          acc[i][j] = fmaf(a[i].x, b[j].x, acc[i][j]);
          acc[i][j] = fmaf(a[i].y, b[j].y, acc[i][j]);
          acc[i][j] = fmaf(a[i].z, b[j].z, acc[i][j]);
          acc[i][j] = fmaf(a[i].w, b[j].w, acc[i][j]);
        }
    }
  }
#pragma unroll
  for (int j = 0; j < 4; ++j) {
    int n = bn + tn + 16 * j;
    float bv = bias[n];
#pragma unroll
    for (int i = 0; i < 4; ++i) {
      int m = bm + tm + 16 * i;
      float val = acc[i][j] + bv;
      float zv = zin[(size_t)m * Nc + n];
      val = zv + (val - zv);  // straight-through arithmetic, fp32 strict
      C[(size_t)m * Nc + n] = val;
    }
  }
}

// ---------------- MFMA similarity + argmax ----------------------------
// Block: 128 tokens x 1024 codes (grid 512 = 256 mtiles x 2 code-halves).
// 4 waves 2x2, wave-tile 64x64 via mfma_f32_32x32x16_f16.
// sim = acc_hh + acc_x/2048 (Markidis fp16 split, err ~1e-8).
// Per 128-code tile: sims -> LDS [m][65] (odd stride), per-token scan keeps
// running best in regs; partial (best,idx) per code-half -> ws.
#define SIMK_BM 128
#define SIMK_BN 128
#define LDH 40  // halves per LDS row: 32 data + 8 pad = 80 B (bank-step 20)

__global__ __launch_bounds__(256, 2) void k_sim_argmax(
    const _Float16* __restrict__ Apack,  // token rows: 1024 halves = hi|lo
    const _Float16* __restrict__ Bhi, const _Float16* __restrict__ Blo,
    float* __restrict__ pv, int* __restrict__ pn) {
  __shared__ __align__(16) _Float16 sm[4 * 128 * LDH];  // 40960 B
  _Float16* sAh = sm;
  _Float16* sAl = sm + 128 * LDH;
  _Float16* sBh = sm + 2 * 128 * LDH;
  _Float16* sBl = sm + 3 * 128 * LDH;
  float* sC = (float*)sm;  // aliased: [128][65] fp32 = 33280 B

  const int tid = threadIdx.x;
  const int w = tid >> 6, l = tid & 63;
  const int wm = w >> 1, wn = w & 1;
  const int lm = l & 31, lh = l >> 5;
  const int s = blockIdx.x & 1;
  const int tokbase = (blockIdx.x >> 1) * SIMK_BM;
  const int code0 = s * (NCODE / 2);
  const int srow0 = tid >> 2, sq = tid & 3;  // staging: row, 16B-chunk
  const int t_red = tid >> 1, h_red = tid & 1;

  float bestv = -2.0f;
  int bestn = 0;

  for (int nt = 0; nt < NCODE / 2; nt += SIMK_BN) {
    f32x16 aHH[2][2], aX[2][2];
#pragma unroll
    for (int mb = 0; mb < 2; ++mb)
#pragma unroll
      for (int nb = 0; nb < 2; ++nb) {
        aHH[mb][nb] = (f32x16)0.0f;
        aX[mb][nb] = (f32x16)0.0f;
      }
    for (int ks = 0; ks < DIM; ks += 32) {
      __syncthreads();
      // stage A(hi,lo) and B(hi,lo): 128 rows x 32 halves each
#pragma unroll
      for (int i = 0; i < 2; ++i) {
        int row = srow0 + i * 64;
        const _Float16* gA =
            Apack + (size_t)(tokbase + row) * 1024 + ks + sq * 8;
        *(f16x8*)(&sAh[row * LDH + sq * 8]) = *(const f16x8*)(gA);
        *(f16x8*)(&sAl[row * LDH + sq * 8]) = *(const f16x8*)(gA + 512);
        const size_t crow = (size_t)(code0 + nt + row) * DIM + ks + sq * 8;
        *(f16x8*)(&sBh[row * LDH + sq * 8]) = *(const f16x8*)(Bhi + crow);
        *(f16x8*)(&sBl[row * LDH + sq * 8]) = *(const f16x8*)(Blo + crow);
      }
      __syncthreads();
#pragma unroll
      for (int c = 0; c < 2; ++c) {
        const int ko = c * 16 + lh * 8;
        f16x8 ah[2], al[2], bh[2], bl[2];
#pragma unroll
        for (int mb = 0; mb < 2; ++mb) {
          int r = wm * 64 + mb * 32 + lm;
          ah[mb] = *(const f16x8*)(&sAh[r * LDH + ko]);
          al[mb] = *(const f16x8*)(&sAl[r * LDH + ko]);
        }
#pragma unroll
        for (int nb = 0; nb < 2; ++nb) {
          int r = wn * 64 + nb * 32 + lm;
          bh[nb] = *(const f16x8*)(&sBh[r * LDH + ko]);
          bl[nb] = *(const f16x8*)(&sBl[r * LDH + ko]);
        }
#pragma unroll
        for (int mb = 0; mb < 2; ++mb)
#pragma unroll
          for (int nb = 0; nb < 2; ++nb) {
            aHH[mb][nb] = __builtin_amdgcn_mfma_f32_32x32x16_f16(
                ah[mb], bh[nb], aHH[mb][nb], 0, 0, 0);
            aX[mb][nb] = __builtin_amdgcn_mfma_f32_32x32x16_f16(
                ah[mb], bl[nb], aX[mb][nb], 0, 0, 0);
            aX[mb][nb] = __builtin_amdgcn_mfma_f32_32x32x16_f16(
                al[mb], bh[nb], aX[mb][nb], 0, 0, 0);
          }
      }
    }
    // epilogue: two n-halves through LDS (aliased over staging region)
#pragma unroll
    for (int p = 0; p < 2; ++p) {
      __syncthreads();  // staging frag reads (p=0) / reduce reads (p=1) done
      if (wn == p) {
#pragma unroll
        for (int mb = 0; mb < 2; ++mb)
#pragma unroll
          for (int nb = 0; nb < 2; ++nb) {
            int nl = nb * 32 + lm;
#pragma unroll
            for (int r = 0; r < 16; ++r) {
              int m = wm * 64 + mb * 32 + (r & 3) + 8 * (r >> 2) + 4 * lh;
              float v = aHH[mb][nb][r] + aX[mb][nb][r] * (1.0f / 2048.0f);
              sC[m * 65 + nl] = v;
            }
          }
      }
      __syncthreads();
      const float* rowp = &sC[t_red * 65 + h_red * 32];
      int nbase = code0 + nt + p * 64 + h_red * 32;
#pragma unroll
      for (int i = 0; i < 32; ++i) {
        float v = rowp[i];
        if (v > bestv) {  // n scanned ascending: '>' keeps first occurrence
          bestv = v;
          bestn = nbase + i;
        }
      }
    }
  }
  // combine the 2 threads per token (h_red halves); tie -> smaller index
  float ov = __shfl_xor(bestv, 1);
  int on = __shfl_xor(bestn, 1);
  if (ov > bestv || (ov == bestv && on < bestn)) {
    bestv = ov;
    bestn = on;
  }
  if (h_red == 0) {
    int gt = tokbase + t_red;
    pv[(size_t)s * BS_TOK + gt] = bestv;
    pn[(size_t)s * BS_TOK + gt] = bestn;
  }
}

// ---------------- combine the two code-half partials ------------------
__global__ __launch_bounds__(256) void k_combine(
    const float* __restrict__ pv, const int* __restrict__ pn,
    int* __restrict__ idx, float* __restrict__ idxf) {
  int t = blockIdx.x * 256 + threadIdx.x;
  float v0 = pv[t], v1 = pv[BS_TOK + t];
  int n0 = pn[t], n1 = pn[BS_TOK + t];
  // half-0 indices are all smaller: '>=' keeps smaller index on exact tie
  int n = (v0 >= v1) ? n0 : n1;
  idx[t] = n;
  idxf[t] = (float)n;
}

extern "C" void kernel_launch(void* const* d_in, const int* in_sizes, int n_in,
                              void* d_out, int out_size, void* d_ws,
                              size_t ws_size, hipStream_t stream) {
  const float* z = (const float*)d_in[0];
  // d_in[1] = mask, unused
  const float* W_in = (const float*)d_in[2];
  const float* b_in = (const float*)d_in[3];
  const float* W_out = (const float*)d_in[4];
  const float* b_out = (const float*)d_in[5];
  const float* emb = (const float*)d_in[6];

  float* out = (float*)d_out;
  float* zq = out;                           // 32768*512 fp32 (final output)
  float* idxf = out + (size_t)BS_TOK * DIM;  // 32768 fp32 indices

  // ws layout (~4.64 MB): embhi | emblo | pv[2] | pn[2] | idx
  _Float16* embhi = (_Float16*)d_ws;
  _Float16* emblo = embhi + (size_t)NCODE * DIM;
  float* pv = (float*)(emblo + (size_t)NCODE * DIM);
  int* pn = (int*)(pv + 2 * (size_t)BS_TOK);
  int* idx = pn + 2 * (size_t)BS_TOK;

  // zf fp32 lives in the zq region; then packed in-place to fp16 hi|lo rows
  float* zf = zq;
  _Float16* zf16 = (_Float16*)zf;  // row stride 1024 halves: [hi 512|lo 512]

  // 1) normalize + split codebook rows -> ws
  k_rownorm_split<<<NCODE, 256, 0, stream>>>(emb, embhi, emblo, DIM);
  // 2) zf = z @ W_in^T + b_in (fp32)
  k_gemm_in<<<dim3(DIM / 64, BS_TOK / 64), 256, 0, stream>>>(z, W_in, b_in,
                                                             zf);
  // 3) normalize zf rows, split to fp16 hi/lo IN-PLACE (packed rows)
  k_rownorm_split<<<BS_TOK, 256, 0, stream>>>(zf, zf16, zf16 + 512, 1024);
  // 4) MFMA similarity + argmax (2 code-halves per token tile)
  k_sim_argmax<<<(BS_TOK / SIMK_BM) * 2, 256, 0, stream>>>(zf16, embhi, emblo,
                                                           pv, pn);
  // 5) combine partials -> idx (ws) + idxf (d_out)
  k_combine<<<BS_TOK / 256, 256, 0, stream>>>(pv, pn, idx, idxf);
  // 6) zq = emb_n[idx] @ W_out^T + b_out (+ straight-through), overwrites zf
  k_gemm_gather<<<dim3(DIM / 64, BS_TOK / 64), 256, 0, stream>>>(
      embhi, emblo, W_out, b_out, zq, idx, z);
}

// Round 3
// 531.217 us; speedup vs baseline: 5.2040x; 1.6901x over previous
//
#include <hip/hip_runtime.h>
#include <math.h>

// Problem constants (B=16, S=2048, L=E=512, N=2048)
#define BS_TOK 32768
#define DIM 512
#define NCODE 2048

typedef _Float16 f16x8 __attribute__((ext_vector_type(8)));
typedef _Float16 f16x4 __attribute__((ext_vector_type(4)));
typedef float f32x16 __attribute__((ext_vector_type(16)));

#define LDH 40  // halves per LDS row: 32 data + 8 pad = 80 B

// ---------------- row L2 normalize + fp16 hi/lo split ----------------
// one block (256 threads) per row of 512. Writes hi[t], lo[t] fp16 arrays
// (row stride rstride halves). Safe for in-place overwrite of `in` because
// all reads complete before the __syncthreads() that precedes writes.
__global__ __launch_bounds__(256) void k_rownorm_split(
    const float* __restrict__ in, _Float16* __restrict__ hi,
    _Float16* __restrict__ lo, int rstride) {
  const int r = blockIdx.x;
  const int t = threadIdx.x;
  const float* row = in + (size_t)r * DIM;
  float v0 = row[t];
  float v1 = row[t + 256];
  float s = v0 * v0 + v1 * v1;
#pragma unroll
  for (int off = 32; off > 0; off >>= 1) s += __shfl_down(s, off, 64);
  __shared__ float ls[4];
  if ((t & 63) == 0) ls[t >> 6] = s;
  __syncthreads();  // also fences: all global reads of this row are done
  float tot = ls[0] + ls[1] + ls[2] + ls[3];
  float sc = 1.0f / fmaxf(sqrtf(tot), 1e-12f);
  float x0 = v0 * sc, x1 = v1 * sc;
  _Float16 h0 = (_Float16)x0;
  _Float16 h1 = (_Float16)x1;
  _Float16 e0 = (_Float16)((x0 - (float)h0) * 2048.0f);
  _Float16 e1 = (_Float16)((x1 - (float)h1) * 2048.0f);
  _Float16* hrow = hi + (size_t)r * rstride;
  _Float16* lrow = lo + (size_t)r * rstride;
  hrow[t] = h0;
  hrow[t + 256] = h1;
  lrow[t] = e0;
  lrow[t + 256] = e1;
}

// ---------------- fp32 -> fp16 hi/lo elementwise split (weights) ------
__global__ __launch_bounds__(256) void k_split_w(const float* __restrict__ w,
                                                 _Float16* __restrict__ hi,
                                                 _Float16* __restrict__ lo) {
  int t = (blockIdx.x * 256 + threadIdx.x) * 4;
  float4 v = *(const float4*)(w + t);
  f16x4 h, l;
  h.x = (_Float16)v.x; l.x = (_Float16)((v.x - (float)h.x) * 2048.0f);
  h.y = (_Float16)v.y; l.y = (_Float16)((v.y - (float)h.y) * 2048.0f);
  h.z = (_Float16)v.z; l.z = (_Float16)((v.z - (float)h.z) * 2048.0f);
  h.w = (_Float16)v.w; l.w = (_Float16)((v.w - (float)h.w) * 2048.0f);
  *(f16x4*)(hi + t) = h;
  *(f16x4*)(lo + t) = l;
}

// ---------------- MFMA split GEMM: input projection -------------------
// C[m,n] = sum_k A[m,k]*B[n,k] + bias[n], A fp32 (split on the fly),
// B pre-split hi/lo fp16. Tile 128x128, BK=32, 4 waves 2x2, wave 64x64.
__global__ __launch_bounds__(256, 2) void k_gemm_mfma_in(
    const float* __restrict__ A, const _Float16* __restrict__ Bhi,
    const _Float16* __restrict__ Blo, const float* __restrict__ bias,
    float* __restrict__ C) {
  __shared__ __align__(16) _Float16 sm[4 * 128 * LDH];  // 40960 B
  _Float16* sAh = sm;
  _Float16* sAl = sm + 128 * LDH;
  _Float16* sBh = sm + 2 * 128 * LDH;
  _Float16* sBl = sm + 3 * 128 * LDH;
  const int tid = threadIdx.x;
  const int w = tid >> 6, l = tid & 63;
  const int wm = w >> 1, wn = w & 1;
  const int lm = l & 31, lh = l >> 5;
  const int m0 = blockIdx.y * 128;
  const int n0 = blockIdx.x * 128;
  f32x16 aHH[2][2], aX[2][2];
#pragma unroll
  for (int mb = 0; mb < 2; ++mb)
#pragma unroll
    for (int nb = 0; nb < 2; ++nb) {
      aHH[mb][nb] = (f32x16)0.0f;
      aX[mb][nb] = (f32x16)0.0f;
    }
  for (int ks = 0; ks < DIM; ks += 32) {
    __syncthreads();
    // stage A: 128 rows x 32 fp32 -> convert to hi/lo (4 float4/thread)
#pragma unroll
    for (int i = 0; i < 4; ++i) {
      int lin = tid + i * 256;
      int row = lin >> 3;
      int c4 = (lin & 7) << 2;
      float4 v = *(const float4*)(A + (size_t)(m0 + row) * DIM + ks + c4);
      f16x4 h, lo4;
      h.x = (_Float16)v.x; lo4.x = (_Float16)((v.x - (float)h.x) * 2048.0f);
      h.y = (_Float16)v.y; lo4.y = (_Float16)((v.y - (float)h.y) * 2048.0f);
      h.z = (_Float16)v.z; lo4.z = (_Float16)((v.z - (float)h.z) * 2048.0f);
      h.w = (_Float16)v.w; lo4.w = (_Float16)((v.w - (float)h.w) * 2048.0f);
      *(f16x4*)(&sAh[row * LDH + c4]) = h;
      *(f16x4*)(&sAl[row * LDH + c4]) = lo4;
    }
    // stage B: 128 rows x 32 halves hi+lo (2 f16x8/thread each)
#pragma unroll
    for (int i = 0; i < 2; ++i) {
      int lin = tid + i * 256;
      int row = lin >> 2;
      int q = (lin & 3) * 8;
      const size_t g = (size_t)(n0 + row) * DIM + ks + q;
      *(f16x8*)(&sBh[row * LDH + q]) = *(const f16x8*)(Bhi + g);
      *(f16x8*)(&sBl[row * LDH + q]) = *(const f16x8*)(Blo + g);
    }
    __syncthreads();
#pragma unroll
    for (int c = 0; c < 2; ++c) {
      const int ko = c * 16 + lh * 8;
      f16x8 ah[2], al[2], bh[2], bl[2];
#pragma unroll
      for (int mb = 0; mb < 2; ++mb) {
        int r = wm * 64 + mb * 32 + lm;
        ah[mb] = *(const f16x8*)(&sAh[r * LDH + ko]);
        al[mb] = *(const f16x8*)(&sAl[r * LDH + ko]);
      }
#pragma unroll
      for (int nb = 0; nb < 2; ++nb) {
        int r = wn * 64 + nb * 32 + lm;
        bh[nb] = *(const f16x8*)(&sBh[r * LDH + ko]);
        bl[nb] = *(const f16x8*)(&sBl[r * LDH + ko]);
      }
#pragma unroll
      for (int mb = 0; mb < 2; ++mb)
#pragma unroll
        for (int nb = 0; nb < 2; ++nb) {
          aHH[mb][nb] = __builtin_amdgcn_mfma_f32_32x32x16_f16(
              ah[mb], bh[nb], aHH[mb][nb], 0, 0, 0);
          aX[mb][nb] = __builtin_amdgcn_mfma_f32_32x32x16_f16(
              ah[mb], bl[nb], aX[mb][nb], 0, 0, 0);
          aX[mb][nb] = __builtin_amdgcn_mfma_f32_32x32x16_f16(
              al[mb], bh[nb], aX[mb][nb], 0, 0, 0);
        }
    }
  }
#pragma unroll
  for (int nb = 0; nb < 2; ++nb) {
    int n = n0 + wn * 64 + nb * 32 + lm;
    float bv = bias[n];
#pragma unroll
    for (int mb = 0; mb < 2; ++mb)
#pragma unroll
      for (int r = 0; r < 16; ++r) {
        int m = m0 + wm * 64 + mb * 32 + (r & 3) + 8 * (r >> 2) + 4 * lh;
        C[(size_t)m * DIM + n] =
            aHH[mb][nb][r] + aX[mb][nb][r] * (1.0f / 2048.0f) + bv;
      }
  }
}

// ---------------- MFMA split GEMM: gathered output projection ---------
// A rows = embhi/emblo[gather[m]]; epilogue does strict fp32
// straight-through: out = z + ((acc + bias) - z).
__global__ __launch_bounds__(256, 2) void k_gemm_mfma_gather(
    const _Float16* __restrict__ Ahi, const _Float16* __restrict__ Alo,
    const _Float16* __restrict__ Bhi, const _Float16* __restrict__ Blo,
    const float* __restrict__ bias, float* __restrict__ C,
    const int* __restrict__ gather, const float* __restrict__ zin) {
  __shared__ __align__(16) _Float16 sm[4 * 128 * LDH];
  __shared__ int gidx[128];
  _Float16* sAh = sm;
  _Float16* sAl = sm + 128 * LDH;
  _Float16* sBh = sm + 2 * 128 * LDH;
  _Float16* sBl = sm + 3 * 128 * LDH;
  const int tid = threadIdx.x;
  const int w = tid >> 6, l = tid & 63;
  const int wm = w >> 1, wn = w & 1;
  const int lm = l & 31, lh = l >> 5;
  const int m0 = blockIdx.y * 128;
  const int n0 = blockIdx.x * 128;
  if (tid < 128) gidx[tid] = gather[m0 + tid];
  f32x16 aHH[2][2], aX[2][2];
#pragma unroll
  for (int mb = 0; mb < 2; ++mb)
#pragma unroll
    for (int nb = 0; nb < 2; ++nb) {
      aHH[mb][nb] = (f32x16)0.0f;
      aX[mb][nb] = (f32x16)0.0f;
    }
  for (int ks = 0; ks < DIM; ks += 32) {
    __syncthreads();  // first iter also fences gidx
#pragma unroll
    for (int i = 0; i < 2; ++i) {
      int lin = tid + i * 256;
      int row = lin >> 2;
      int q = (lin & 3) * 8;
      const size_t ga = (size_t)gidx[row] * DIM + ks + q;
      *(f16x8*)(&sAh[row * LDH + q]) = *(const f16x8*)(Ahi + ga);
      *(f16x8*)(&sAl[row * LDH + q]) = *(const f16x8*)(Alo + ga);
      const size_t gb = (size_t)(n0 + row) * DIM + ks + q;
      *(f16x8*)(&sBh[row * LDH + q]) = *(const f16x8*)(Bhi + gb);
      *(f16x8*)(&sBl[row * LDH + q]) = *(const f16x8*)(Blo + gb);
    }
    __syncthreads();
#pragma unroll
    for (int c = 0; c < 2; ++c) {
      const int ko = c * 16 + lh * 8;
      f16x8 ah[2], al[2], bh[2], bl[2];
#pragma unroll
      for (int mb = 0; mb < 2; ++mb) {
        int r = wm * 64 + mb * 32 + lm;
        ah[mb] = *(const f16x8*)(&sAh[r * LDH + ko]);
        al[mb] = *(const f16x8*)(&sAl[r * LDH + ko]);
      }
#pragma unroll
      for (int nb = 0; nb < 2; ++nb) {
        int r = wn * 64 + nb * 32 + lm;
        bh[nb] = *(const f16x8*)(&sBh[r * LDH + ko]);
        bl[nb] = *(const f16x8*)(&sBl[r * LDH + ko]);
      }
#pragma unroll
      for (int mb = 0; mb < 2; ++mb)
#pragma unroll
        for (int nb = 0; nb < 2; ++nb) {
          aHH[mb][nb] = __builtin_amdgcn_mfma_f32_32x32x16_f16(
              ah[mb], bh[nb], aHH[mb][nb], 0, 0, 0);
          aX[mb][nb] = __builtin_amdgcn_mfma_f32_32x32x16_f16(
              ah[mb], bl[nb], aX[mb][nb], 0, 0, 0);
          aX[mb][nb] = __builtin_amdgcn_mfma_f32_32x32x16_f16(
              al[mb], bh[nb], aX[mb][nb], 0, 0, 0);
        }
    }
  }
#pragma unroll
  for (int nb = 0; nb < 2; ++nb) {
    int n = n0 + wn * 64 + nb * 32 + lm;
    float bv = bias[n];
#pragma unroll
    for (int mb = 0; mb < 2; ++mb)
#pragma unroll
      for (int r = 0; r < 16; ++r) {
        int m = m0 + wm * 64 + mb * 32 + (r & 3) + 8 * (r >> 2) + 4 * lh;
        float val = aHH[mb][nb][r] + aX[mb][nb][r] * (1.0f / 2048.0f) + bv;
        float zv = zin[(size_t)m * DIM + n];
        C[(size_t)m * DIM + n] = zv + (val - zv);
      }
  }
}

// ---------------- MFMA similarity + argmax ----------------------------
// Block: 128 tokens x 1024 codes (grid 512 = 256 mtiles x 2 code-halves).
// 4 waves 2x2, wave-tile 64x64 via mfma_f32_32x32x16_f16.
// sim = acc_hh + acc_x/2048 (Markidis fp16 split, err ~1e-8).
#define SIMK_BM 128
#define SIMK_BN 128

__global__ __launch_bounds__(256, 2) void k_sim_argmax(
    const _Float16* __restrict__ Apack,  // token rows: 1024 halves = hi|lo
    const _Float16* __restrict__ Bhi, const _Float16* __restrict__ Blo,
    float* __restrict__ pv, int* __restrict__ pn) {
  __shared__ __align__(16) _Float16 sm[4 * 128 * LDH];  // 40960 B
  _Float16* sAh = sm;
  _Float16* sAl = sm + 128 * LDH;
  _Float16* sBh = sm + 2 * 128 * LDH;
  _Float16* sBl = sm + 3 * 128 * LDH;
  float* sC = (float*)sm;  // aliased: [128][65] fp32 = 33280 B

  const int tid = threadIdx.x;
  const int w = tid >> 6, l = tid & 63;
  const int wm = w >> 1, wn = w & 1;
  const int lm = l & 31, lh = l >> 5;
  const int s = blockIdx.x & 1;
  const int tokbase = (blockIdx.x >> 1) * SIMK_BM;
  const int code0 = s * (NCODE / 2);
  const int srow0 = tid >> 2, sq = tid & 3;
  const int t_red = tid >> 1, h_red = tid & 1;

  float bestv = -2.0f;
  int bestn = 0;

  for (int nt = 0; nt < NCODE / 2; nt += SIMK_BN) {
    f32x16 aHH[2][2], aX[2][2];
#pragma unroll
    for (int mb = 0; mb < 2; ++mb)
#pragma unroll
      for (int nb = 0; nb < 2; ++nb) {
        aHH[mb][nb] = (f32x16)0.0f;
        aX[mb][nb] = (f32x16)0.0f;
      }
    for (int ks = 0; ks < DIM; ks += 32) {
      __syncthreads();
#pragma unroll
      for (int i = 0; i < 2; ++i) {
        int row = srow0 + i * 64;
        const _Float16* gA =
            Apack + (size_t)(tokbase + row) * 1024 + ks + sq * 8;
        *(f16x8*)(&sAh[row * LDH + sq * 8]) = *(const f16x8*)(gA);
        *(f16x8*)(&sAl[row * LDH + sq * 8]) = *(const f16x8*)(gA + 512);
        const size_t crow = (size_t)(code0 + nt + row) * DIM + ks + sq * 8;
        *(f16x8*)(&sBh[row * LDH + sq * 8]) = *(const f16x8*)(Bhi + crow);
        *(f16x8*)(&sBl[row * LDH + sq * 8]) = *(const f16x8*)(Blo + crow);
      }
      __syncthreads();
#pragma unroll
      for (int c = 0; c < 2; ++c) {
        const int ko = c * 16 + lh * 8;
        f16x8 ah[2], al[2], bh[2], bl[2];
#pragma unroll
        for (int mb = 0; mb < 2; ++mb) {
          int r = wm * 64 + mb * 32 + lm;
          ah[mb] = *(const f16x8*)(&sAh[r * LDH + ko]);
          al[mb] = *(const f16x8*)(&sAl[r * LDH + ko]);
        }
#pragma unroll
        for (int nb = 0; nb < 2; ++nb) {
          int r = wn * 64 + nb * 32 + lm;
          bh[nb] = *(const f16x8*)(&sBh[r * LDH + ko]);
          bl[nb] = *(const f16x8*)(&sBl[r * LDH + ko]);
        }
#pragma unroll
        for (int mb = 0; mb < 2; ++mb)
#pragma unroll
          for (int nb = 0; nb < 2; ++nb) {
            aHH[mb][nb] = __builtin_amdgcn_mfma_f32_32x32x16_f16(
                ah[mb], bh[nb], aHH[mb][nb], 0, 0, 0);
            aX[mb][nb] = __builtin_amdgcn_mfma_f32_32x32x16_f16(
                ah[mb], bl[nb], aX[mb][nb], 0, 0, 0);
            aX[mb][nb] = __builtin_amdgcn_mfma_f32_32x32x16_f16(
                al[mb], bh[nb], aX[mb][nb], 0, 0, 0);
          }
      }
    }
    // epilogue: two n-halves through LDS (aliased over staging region)
#pragma unroll
    for (int p = 0; p < 2; ++p) {
      __syncthreads();
      if (wn == p) {
#pragma unroll
        for (int mb = 0; mb < 2; ++mb)
#pragma unroll
          for (int nb = 0; nb < 2; ++nb) {
            int nl = nb * 32 + lm;
#pragma unroll
            for (int r = 0; r < 16; ++r) {
              int m = wm * 64 + mb * 32 + (r & 3) + 8 * (r >> 2) + 4 * lh;
              float v = aHH[mb][nb][r] + aX[mb][nb][r] * (1.0f / 2048.0f);
              sC[m * 65 + nl] = v;
            }
          }
      }
      __syncthreads();
      const float* rowp = &sC[t_red * 65 + h_red * 32];
      int nbase = code0 + nt + p * 64 + h_red * 32;
#pragma unroll
      for (int i = 0; i < 32; ++i) {
        float v = rowp[i];
        if (v > bestv) {  // n scanned ascending: '>' keeps first occurrence
          bestv = v;
          bestn = nbase + i;
        }
      }
    }
  }
  float ov = __shfl_xor(bestv, 1);
  int on = __shfl_xor(bestn, 1);
  if (ov > bestv || (ov == bestv && on < bestn)) {
    bestv = ov;
    bestn = on;
  }
  if (h_red == 0) {
    int gt = tokbase + t_red;
    pv[(size_t)s * BS_TOK + gt] = bestv;
    pn[(size_t)s * BS_TOK + gt] = bestn;
  }
}

// ---------------- combine the two code-half partials ------------------
__global__ __launch_bounds__(256) void k_combine(
    const float* __restrict__ pv, const int* __restrict__ pn,
    int* __restrict__ idx, float* __restrict__ idxf) {
  int t = blockIdx.x * 256 + threadIdx.x;
  float v0 = pv[t], v1 = pv[BS_TOK + t];
  int n0 = pn[t], n1 = pn[BS_TOK + t];
  int n = (v0 >= v1) ? n0 : n1;  // half-0 indices smaller: tie -> smaller
  idx[t] = n;
  idxf[t] = (float)n;
}

extern "C" void kernel_launch(void* const* d_in, const int* in_sizes, int n_in,
                              void* d_out, int out_size, void* d_ws,
                              size_t ws_size, hipStream_t stream) {
  const float* z = (const float*)d_in[0];
  // d_in[1] = mask, unused
  const float* W_in = (const float*)d_in[2];
  const float* b_in = (const float*)d_in[3];
  const float* W_out = (const float*)d_in[4];
  const float* b_out = (const float*)d_in[5];
  const float* emb = (const float*)d_in[6];

  float* out = (float*)d_out;
  float* zq = out;                           // 32768*512 fp32 (final output)
  float* idxf = out + (size_t)BS_TOK * DIM;  // 32768 fp32 indices

  // ws layout (~6.6 MB): embhi|emblo|winhi|winlo|wouthi|woutlo|pv|pn|idx
  _Float16* embhi = (_Float16*)d_ws;
  _Float16* emblo = embhi + (size_t)NCODE * DIM;
  _Float16* winhi = emblo + (size_t)NCODE * DIM;
  _Float16* winlo = winhi + (size_t)DIM * DIM;
  _Float16* wouthi = winlo + (size_t)DIM * DIM;
  _Float16* woutlo = wouthi + (size_t)DIM * DIM;
  float* pv = (float*)(woutlo + (size_t)DIM * DIM);
  int* pn = (int*)(pv + 2 * (size_t)BS_TOK);
  int* idx = pn + 2 * (size_t)BS_TOK;

  // zf fp32 lives in the zq region; then packed in-place to fp16 hi|lo rows
  float* zf = zq;
  _Float16* zf16 = (_Float16*)zf;  // row stride 1024 halves: [hi 512|lo 512]

  // 0) split weights
  k_split_w<<<DIM * DIM / 1024, 256, 0, stream>>>(W_in, winhi, winlo);
  k_split_w<<<DIM * DIM / 1024, 256, 0, stream>>>(W_out, wouthi, woutlo);
  // 1) normalize + split codebook rows -> ws
  k_rownorm_split<<<NCODE, 256, 0, stream>>>(emb, embhi, emblo, DIM);
  // 2) zf = z @ W_in^T + b_in (MFMA fp16-split, A converted on the fly)
  k_gemm_mfma_in<<<dim3(DIM / 128, BS_TOK / 128), 256, 0, stream>>>(
      z, winhi, winlo, b_in, zf);
  // 3) normalize zf rows, split to fp16 hi/lo IN-PLACE (packed rows)
  k_rownorm_split<<<BS_TOK, 256, 0, stream>>>(zf, zf16, zf16 + 512, 1024);
  // 4) MFMA similarity + argmax (2 code-halves per token tile)
  k_sim_argmax<<<(BS_TOK / SIMK_BM) * 2, 256, 0, stream>>>(zf16, embhi, emblo,
                                                           pv, pn);
  // 5) combine partials -> idx (ws) + idxf (d_out)
  k_combine<<<BS_TOK / 256, 256, 0, stream>>>(pv, pn, idx, idxf);
  // 6) zq = emb_n[idx] @ W_out^T + b_out (+ straight-through), overwrites zf
  k_gemm_mfma_gather<<<dim3(DIM / 128, BS_TOK / 128), 256, 0, stream>>>(
      embhi, emblo, wouthi, woutlo, b_out, zq, idx, z);
}